// Round 12
// baseline (105.521 us; speedup 1.0000x reference)
//
#include <hip/hip_runtime.h>
#include <math.h>

#define NB 8
#define H 64
#define W 64
#define C 128
#define G 8
#define GC 16
#define P 9
#define NPIX (NB * H * W)     // 32768
#define N_OFF 144
#define N_MSK 72
#define PXB 32
#define RECW 232              // record row stride in u16 (464 B)
#define PK_IN_ELEMS   (8 * 4 * 64 * 8)    // 16384
#define PK_COMB_ELEMS (14 * 4 * 64 * 8)   // 28672
#define PK_OUT_ELEMS  (8 * 4 * 64 * 8)    // 16384

using bf16x8 = __attribute__((ext_vector_type(8))) short;
using f32x4  = __attribute__((ext_vector_type(4))) float;
using u32x4  = __attribute__((ext_vector_type(4))) unsigned;

__device__ __forceinline__ short f2bf(float f) {
    union { float fv; unsigned u; } v; v.fv = f;
    unsigned r = v.u + 0x7fffu + ((v.u >> 16) & 1u);
    return (short)(r >> 16);
}

// ---------------- K0: pack weights into MFMA B-fragment order, bf16 --------
__global__ __launch_bounds__(256) void k_pack(
    const float* __restrict__ w_in, const float* __restrict__ w_off,
    const float* __restrict__ w_msk, const float* __restrict__ w_out,
    short* __restrict__ pk_in, short* __restrict__ pk_comb, short* __restrict__ pk_out)
{
    const int tid = blockIdx.x * 256 + threadIdx.x;
    int p, which;
    if (tid < PK_IN_ELEMS) { p = tid; which = 0; }
    else if (tid < PK_IN_ELEMS + PK_COMB_ELEMS) { p = tid - PK_IN_ELEMS; which = 1; }
    else if (tid < PK_IN_ELEMS + PK_COMB_ELEMS + PK_OUT_ELEMS) { p = tid - PK_IN_ELEMS - PK_COMB_ELEMS; which = 2; }
    else return;
    const int e = p & 7, lane = (p >> 3) & 63, kt = (p >> 9) & 3, nt = p >> 11;
    const int k = kt * 32 + (lane >> 4) * 8 + e;
    const int n = nt * 16 + (lane & 15);
    float v;
    if (which == 0) {
        v = w_in[k * C + n];
        pk_in[p] = f2bf(v);
    } else if (which == 1) {
        if (n < N_OFF) v = w_off[k * N_OFF + n];
        else if (n < N_OFF + N_MSK) v = w_msk[k * N_MSK + (n - N_OFF)];
        else v = 0.f;
        pk_comb[p] = f2bf(v);
    } else {
        v = w_out[k * C + n];
        pk_out[p] = f2bf(v);
    }
}

// ---- K_fm: dwconv+LN+GELU + inproj MFMA -> xproj planar ----
// ----       + offset/mask MFMA + softmax -> 448B/px records in out slots ---
__global__ __launch_bounds__(256, 2) void k_fm(
    const float* __restrict__ x, const float* __restrict__ dw_w,
    const float* __restrict__ dw_b, const float* __restrict__ ln_g,
    const float* __restrict__ ln_b, const short* __restrict__ pk_in,
    const float* __restrict__ b_in, const short* __restrict__ pk_comb,
    const float* __restrict__ b_off, const float* __restrict__ b_msk,
    unsigned short* __restrict__ xproj, float* __restrict__ out)
{
    __shared__ __align__(16) short xa[PXB * C];
    __shared__ __align__(16) short x1s[PXB * C];
    __shared__ unsigned short recs[PXB * RECW];
    __shared__ float part[PXB][8][2];
    __shared__ float stats[PXB][2];

    const int t = threadIdx.x;
    const int n = blockIdx.x & 7;
    const int local = blockIdx.x >> 3;
    const int y = local >> 1;
    const int xb = (local & 1) * PXB;
    const int gpix0 = (n * H + y) * W + xb;

    const int px = t >> 3;
    const int c8 = t & 7;
    const int c0 = c8 * 16;
    const int gpx = gpix0 + px;

    float a[16];
    #pragma unroll
    for (int q = 0; q < 4; ++q) {
        f32x4 v = *(const f32x4*)(dw_b + c0 + q * 4);
        #pragma unroll
        for (int e = 0; e < 4; ++e) a[q * 4 + e] = v[e];
    }
    #pragma unroll
    for (int ky = 0; ky < 3; ++ky) {
        const int yy = y + ky - 1;
        if (yy < 0 || yy >= H) continue;
        #pragma unroll
        for (int kx = 0; kx < 3; ++kx) {
            const int xx = xb + px + kx - 1;
            if (xx < 0 || xx >= W) continue;
            const float* xp = x + ((size_t)(n * H + yy) * W + xx) * C + c0;
            const float* wp = dw_w + (ky * 3 + kx) * C + c0;
            #pragma unroll
            for (int q = 0; q < 4; ++q) {
                f32x4 xv = *(const f32x4*)(xp + q * 4);
                f32x4 wv = *(const f32x4*)(wp + q * 4);
                #pragma unroll
                for (int e = 0; e < 4; ++e)
                    a[q * 4 + e] = fmaf(xv[e], wv[e], a[q * 4 + e]);
            }
        }
    }
    {
        const float* cp = x + (size_t)gpx * C + c0;
        const int sw = (px & 7) << 4;
        #pragma unroll
        for (int h = 0; h < 2; ++h) {
            f32x4 v0 = *(const f32x4*)(cp + h * 8);
            f32x4 v1 = *(const f32x4*)(cp + h * 8 + 4);
            bf16x8 pk;
            #pragma unroll
            for (int e = 0; e < 4; ++e) { pk[e] = f2bf(v0[e]); pk[4 + e] = f2bf(v1[e]); }
            *(bf16x8*)((char*)xa + px * 256 + ((c8 * 32 + h * 16) ^ sw)) = pk;
        }
    }
    {
        float s = 0.f, sq = 0.f;
        #pragma unroll
        for (int cc = 0; cc < 16; ++cc) { s += a[cc]; sq = fmaf(a[cc], a[cc], sq); }
        part[px][c8][0] = s;
        part[px][c8][1] = sq;
    }
    __syncthreads();
    if (t < PXB) {
        float S = 0.f, Q = 0.f;
        #pragma unroll
        for (int q = 0; q < 8; ++q) { S += part[t][q][0]; Q += part[t][q][1]; }
        const float mu = S * (1.f / C);
        const float va = Q * (1.f / C) - mu * mu;
        stats[t][0] = mu;
        stats[t][1] = rsqrtf(va + 1e-6f);
    }
    __syncthreads();
    {
        const float mu = stats[px][0], rs = stats[px][1];
        const int sw = (px & 7) << 4;
        #pragma unroll
        for (int h = 0; h < 2; ++h) {
            bf16x8 pk;
            #pragma unroll
            for (int e = 0; e < 8; ++e) {
                const int cc = h * 8 + e;
                float v = (a[cc] - mu) * rs * ln_g[c0 + cc] + ln_b[c0 + cc];
                pk[e] = f2bf(v * 0.5f * (1.f + erff(v * 0.70710678118654752f)));
            }
            *(bf16x8*)((char*)x1s + px * 256 + ((c8 * 32 + h * 16) ^ sw)) = pk;
        }
    }
    __syncthreads();

    {
        const int w = t >> 6, l = t & 63;
        const int swA = (l & 7) << 4;
        bf16x8 aA[2][4], aB[2][4];
        #pragma unroll
        for (int mt = 0; mt < 2; ++mt) {
            const int m = mt * 16 + (l & 15);
            #pragma unroll
            for (int kt = 0; kt < 4; ++kt) {
                const int byte = m * 256 + ((kt * 64 + (l >> 4) * 16) ^ swA);
                aA[mt][kt] = *(const bf16x8*)((char*)xa + byte);
                aB[mt][kt] = *(const bf16x8*)((char*)x1s + byte);
            }
        }
        #pragma unroll
        for (int i = 0; i < 2; ++i) {
            const int nt = w + i * 4;
            bf16x8 bf[4];
            const short* bp = pk_in + nt * 2048 + l * 8;
            #pragma unroll
            for (int kt = 0; kt < 4; ++kt) bf[kt] = *(const bf16x8*)(bp + kt * 512);
            const float bias = b_in[nt * 16 + (l & 15)];
            #pragma unroll
            for (int mt = 0; mt < 2; ++mt) {
                f32x4 acc = {0.f, 0.f, 0.f, 0.f};
                #pragma unroll
                for (int kt = 0; kt < 4; ++kt)
                    acc = __builtin_amdgcn_mfma_f32_16x16x32_bf16(aA[mt][kt], bf[kt], acc, 0, 0, 0);
                const int prow = gpix0 + mt * 16 + (l >> 4) * 4;
                #pragma unroll
                for (int r = 0; r < 4; ++r)
                    xproj[(size_t)(nt * NPIX + prow + r) * 16 + (l & 15)] =
                        (unsigned short)f2bf(acc[r] + bias);
            }
        }
        #pragma unroll
        for (int i = 0; i < 4; ++i) {
            const int nt = w + i * 4;
            if (nt < 14) {
                bf16x8 bf[4];
                const short* bp = pk_comb + nt * 2048 + l * 8;
                #pragma unroll
                for (int kt = 0; kt < 4; ++kt) bf[kt] = *(const bf16x8*)(bp + kt * 512);
                const int col = nt * 16 + (l & 15);
                int dcol = col;
                float bias = 0.f;
                bool valid = true;
                if (col < N_OFF) bias = b_off[col];
                else {
                    const int cm = col - N_OFF;
                    if (cm < N_MSK) {
                        const int g = (cm * 57) >> 9;
                        dcol = 144 + g * 10 + (cm - 9 * g);
                        bias = b_msk[cm];
                    } else valid = false;
                }
                #pragma unroll
                for (int mt = 0; mt < 2; ++mt) {
                    f32x4 acc = {0.f, 0.f, 0.f, 0.f};
                    #pragma unroll
                    for (int kt = 0; kt < 4; ++kt)
                        acc = __builtin_amdgcn_mfma_f32_16x16x32_bf16(aB[mt][kt], bf[kt], acc, 0, 0, 0);
                    if (valid) {
                        const int pr0 = mt * 16 + (l >> 4) * 4;
                        #pragma unroll
                        for (int r = 0; r < 4; ++r)
                            recs[(pr0 + r) * RECW + dcol] = (unsigned short)f2bf(acc[r] + bias);
                    }
                }
            }
        }
    }
    __syncthreads();

    {
        const int spx = t >> 3, g = t & 7;
        unsigned short* row = recs + spx * RECW + 144 + g * 10;
        float lg[P];
        #pragma unroll
        for (int p = 0; p < P; ++p) lg[p] = __uint_as_float(((unsigned)row[p]) << 16);
        float mx = lg[0];
        #pragma unroll
        for (int p2 = 1; p2 < P; ++p2) mx = fmaxf(mx, lg[p2]);
        float e[P], s = 0.f;
        #pragma unroll
        for (int p2 = 0; p2 < P; ++p2) { e[p2] = expf(lg[p2] - mx); s += e[p2]; }
        const float inv = 1.0f / s;
        #pragma unroll
        for (int p2 = 0; p2 < P; ++p2) row[p2] = (unsigned short)f2bf(e[p2] * inv);
    }
    __syncthreads();

    {
        const int spx = t >> 3, q0 = t & 7;
        const char* srcL = (const char*)recs + spx * (RECW * 2);
        char* dst = (char*)out + (size_t)(gpix0 + spx) * 512;
        #pragma unroll
        for (int h = 0; h < 4; ++h) {
            const int q = q0 + h * 8;
            if (q < 28)
                *(bf16x8*)(dst + q * 16) = *(const bf16x8*)(srcL + q * 16);
        }
    }
}

// ---- K_samp: 5x5 stencil build (LDS atomics) + windowed gather + out-proj ----
#define PADX 41
#define STW 27
__global__ __launch_bounds__(256, 2) void k_samp(
    const unsigned short* __restrict__ xproj, const short* __restrict__ pk_out,
    const float* __restrict__ b_out, float* __restrict__ out)
{
    __shared__ __align__(16) short smp[PXB * C];            // 8 KB
    __shared__ __align__(16) u32x4 win[2 * 4 * 5 * PADX];   // 26.2 KB
    __shared__ float stc[4 * PXB * STW];                    // 13.8 KB stencils
    __shared__ unsigned char flg[4 * PXB];                  // simple flags

    const int t = threadIdx.x;
    const int n = blockIdx.x & 7;
    const int local = blockIdx.x >> 3;
    const int y = local >> 1;
    const int xb = (local & 1) * PXB;
    const int gpix0 = (n * H + y) * W + xb;
    const int imgbase = n * (H * W);

    const int spx = t & 31;
    const int gl = (t >> 5) & 3;
    const int half = t >> 7;
    const int swz = (spx & 7) << 4;
    const unsigned* slot = (const unsigned*)((const char*)out +
                           (size_t)(gpix0 + spx) * 512);
    float* strow = stc + (gl * 32 + spx) * STW;

    for (int f = 0; f < 2; ++f) {
        // ---- phase 0: zero stencil row (half-split) + flag reset ----
        if (half == 0) {
            #pragma unroll
            for (int w2 = 0; w2 < 14; ++w2) strow[w2] = 0.f;
            flg[gl * 32 + spx] = 1;
        } else {
            #pragma unroll
            for (int w2 = 14; w2 < STW; ++w2) strow[w2] = 0.f;
        }
        __syncthreads();

        // ---- phase 1: stencil build (taps split across halves) ----
        {
            const int g = f * 4 + gl;
            bool ok = true;
            const int p0 = half ? 5 : 0, p1 = half ? 9 : 5;
            for (int p = p0; p < p1; ++p) {
                const unsigned ovp = slot[g * 9 + p];
                const unsigned pu = slot[72 + 5 * g + (p >> 1)];
                const float mk = (p & 1) ? __uint_as_float(pu & 0xffff0000u)
                                         : __uint_as_float(pu << 16);
                const float offx = __uint_as_float(ovp << 16);
                const float offy = __uint_as_float(ovp & 0xffff0000u);
                const float ux = (float)(xb + spx + (p / 3) - 1) + offx;
                const float uy = (float)(y + (p % 3) - 1) + offy;
                const float fx = floorf(ux), fy = floorf(uy);
                const float wx = ux - fx, wy = uy - fy;
                const int x0 = (int)fx, y0 = (int)fy;
                float w00 = mk * (1.f - wx) * (1.f - wy);
                float w10 = mk * wx * (1.f - wy);
                float w01 = mk * (1.f - wx) * wy;
                float w11 = mk * wx * wy;
                if (!((x0 >= 0) & (x0 < W)))       { w00 = 0.f; w01 = 0.f; }
                if (!((x0 >= -1) & (x0 < W - 1)))  { w10 = 0.f; w11 = 0.f; }
                if (!((y0 >= 0) & (y0 < H)))       { w00 = 0.f; w10 = 0.f; }
                if (!((y0 >= -1) & (y0 < H - 1)))  { w01 = 0.f; w11 = 0.f; }
                const int x0c = min(max(x0, 0), W - 1), x1c = min(max(x0 + 1, 0), W - 1);
                const int y0c = min(max(y0, 0), H - 1), y1c = min(max(y0 + 1, 0), H - 1);
                const int rx0 = x0c - (xb + spx) + 2, rx1 = x1c - (xb + spx) + 2;
                const int ry0 = y0c - y + 2, ry1 = y1c - y + 2;
                const bool in00 = ((unsigned)rx0 <= 4u) & ((unsigned)ry0 <= 4u);
                const bool in10 = ((unsigned)rx1 <= 4u) & ((unsigned)ry0 <= 4u);
                const bool in01 = ((unsigned)rx0 <= 4u) & ((unsigned)ry1 <= 4u);
                const bool in11 = ((unsigned)rx1 <= 4u) & ((unsigned)ry1 <= 4u);
                if ((w00 != 0.f && !in00) || (w10 != 0.f && !in10) ||
                    (w01 != 0.f && !in01) || (w11 != 0.f && !in11)) {
                    ok = false;
                } else {
                    if (in00) atomicAdd(strow + ry0 * 5 + rx0, w00);
                    if (in10) atomicAdd(strow + ry0 * 5 + rx1, w10);
                    if (in01) atomicAdd(strow + ry1 * 5 + rx0, w01);
                    if (in11) atomicAdd(strow + ry1 * 5 + rx1, w11);
                }
            }
            if (!ok) flg[gl * 32 + spx] = 0;
        }

        // ---- phase 2: fill window (all threads), uh innermost for coalescing ----
        for (int e = t; e < 1600; e += 256) {
            const int uh = e & 1;
            const int v = e >> 1;            // 0..799
            const int xs = v % 40;
            const int q = v / 40;            // 0..19
            const int rs = q % 5;
            const int gs = q / 5;
            const int row = min(max(y - 2 + rs, 0), H - 1);
            const int col = min(max(xb - 4 + xs, 0), W - 1);
            win[((uh * 4 + gs) * 5 + rs) * PADX + xs] =
                *(const u32x4*)(xproj +
                    ((size_t)((f * 4 + gs) * NPIX + imgbase + row * W + col)) * 16 + uh * 8);
        }
        __syncthreads();

        // ---- phase 3: sample ----
        {
            const int g = f * 4 + gl;
            float acc[8];
            #pragma unroll
            for (int q = 0; q < 8; ++q) acc[q] = 0.f;
            if (flg[gl * 32 + spx]) {
                float cf[25];
                #pragma unroll
                for (int i = 0; i < 25; ++i) cf[i] = strow[i];
                const u32x4* wb = win + (half * 4 + gl) * 5 * PADX + spx + 2;
                #pragma unroll
                for (int rr = 0; rr < 5; ++rr) {
                    #pragma unroll
                    for (int cc = 0; cc < 5; ++cc) {
                        const float cw = cf[rr * 5 + cc];
                        const u32x4 v = wb[rr * PADX + cc];
                        #pragma unroll
                        for (int e = 0; e < 4; ++e) {
                            acc[2 * e]     = fmaf(cw, __uint_as_float(v[e] << 16), acc[2 * e]);
                            acc[2 * e + 1] = fmaf(cw, __uint_as_float(v[e] & 0xffff0000u), acc[2 * e + 1]);
                        }
                    }
                }
            } else {
                // rare fallback: exact per-tap gather from global planes
                const u32x4* plane4 = (const u32x4*)(xproj + (size_t)(g * NPIX + imgbase) * 16);
                for (int p = 0; p < P; ++p) {
                    const unsigned ovp = slot[g * 9 + p];
                    const unsigned pu = slot[72 + 5 * g + (p >> 1)];
                    const float mk = (p & 1) ? __uint_as_float(pu & 0xffff0000u)
                                             : __uint_as_float(pu << 16);
                    const float offx = __uint_as_float(ovp << 16);
                    const float offy = __uint_as_float(ovp & 0xffff0000u);
                    const float ux = (float)(xb + spx + (p / 3) - 1) + offx;
                    const float uy = (float)(y + (p % 3) - 1) + offy;
                    const float fx = floorf(ux), fy = floorf(uy);
                    const float wx = ux - fx, wy = uy - fy;
                    const int x0 = (int)fx, y0 = (int)fy;
                    float w4[4];
                    w4[0] = mk * (1.f - wx) * (1.f - wy);
                    w4[1] = mk * wx * (1.f - wy);
                    w4[2] = mk * (1.f - wx) * wy;
                    w4[3] = mk * wx * wy;
                    if (!((x0 >= 0) & (x0 < W)))       { w4[0] = 0.f; w4[2] = 0.f; }
                    if (!((x0 >= -1) & (x0 < W - 1)))  { w4[1] = 0.f; w4[3] = 0.f; }
                    if (!((y0 >= 0) & (y0 < H)))       { w4[0] = 0.f; w4[1] = 0.f; }
                    if (!((y0 >= -1) & (y0 < H - 1)))  { w4[2] = 0.f; w4[3] = 0.f; }
                    const int xc[2] = { min(max(x0, 0), W - 1), min(max(x0 + 1, 0), W - 1) };
                    const int yc[2] = { min(max(y0, 0), H - 1), min(max(y0 + 1, 0), H - 1) };
                    #pragma unroll
                    for (int cn = 0; cn < 4; ++cn) {
                        const float wgt = w4[cn];
                        if (wgt == 0.f) continue;
                        const u32x4 v = plane4[(size_t)(yc[cn >> 1] * W + xc[cn & 1]) * 2 + half];
                        #pragma unroll
                        for (int e = 0; e < 4; ++e) {
                            acc[2 * e]     = fmaf(wgt, __uint_as_float(v[e] << 16), acc[2 * e]);
                            acc[2 * e + 1] = fmaf(wgt, __uint_as_float(v[e] & 0xffff0000u), acc[2 * e + 1]);
                        }
                    }
                }
            }
            bf16x8 pk;
            #pragma unroll
            for (int e = 0; e < 8; ++e) pk[e] = f2bf(acc[e]);
            *(bf16x8*)((char*)smp + spx * 256 + (((f * 4 + gl) * 32 + half * 16) ^ swz)) = pk;
        }
        __syncthreads();
    }

    // ---- output projection via MFMA (nt-partitioned) ----
    {
        const int w = t >> 6, l = t & 63;
        const int swA = (l & 7) << 4;
        bf16x8 aS[2][4];
        #pragma unroll
        for (int mt = 0; mt < 2; ++mt) {
            const int m = mt * 16 + (l & 15);
            #pragma unroll
            for (int kt = 0; kt < 4; ++kt)
                aS[mt][kt] = *(const bf16x8*)((char*)smp + m * 256 +
                                              ((kt * 64 + (l >> 4) * 16) ^ swA));
        }
        #pragma unroll
        for (int i = 0; i < 2; ++i) {
            const int nt = w + i * 4;
            bf16x8 bf[4];
            const short* bp = pk_out + nt * 2048 + l * 8;
            #pragma unroll
            for (int kt = 0; kt < 4; ++kt) bf[kt] = *(const bf16x8*)(bp + kt * 512);
            const float bias = b_out[nt * 16 + (l & 15)];
            #pragma unroll
            for (int mt = 0; mt < 2; ++mt) {
                f32x4 acc = {0.f, 0.f, 0.f, 0.f};
                #pragma unroll
                for (int kt = 0; kt < 4; ++kt)
                    acc = __builtin_amdgcn_mfma_f32_16x16x32_bf16(aS[mt][kt], bf[kt], acc, 0, 0, 0);
                const int row0 = gpix0 + mt * 16 + (l >> 4) * 4;
                #pragma unroll
                for (int r = 0; r < 4; ++r)
                    out[(size_t)(row0 + r) * C + nt * 16 + (l & 15)] = acc[r] + bias;
            }
        }
    }
}

extern "C" void kernel_launch(void* const* d_in, const int* in_sizes, int n_in,
                              void* d_out, int out_size, void* d_ws, size_t ws_size,
                              hipStream_t stream)
{
    const float* x     = (const float*)d_in[0];
    const float* w_in  = (const float*)d_in[1];
    const float* b_in  = (const float*)d_in[2];
    const float* dw_w  = (const float*)d_in[3];
    const float* dw_b  = (const float*)d_in[4];
    const float* ln_g  = (const float*)d_in[5];
    const float* ln_b  = (const float*)d_in[6];
    const float* w_off = (const float*)d_in[7];
    const float* b_off = (const float*)d_in[8];
    const float* w_msk = (const float*)d_in[9];
    const float* b_msk = (const float*)d_in[10];
    const float* w_out = (const float*)d_in[11];
    const float* b_out = (const float*)d_in[12];

    short* pk_in   = (short*)d_ws;
    short* pk_comb = pk_in + PK_IN_ELEMS;
    short* pk_out  = pk_comb + PK_COMB_ELEMS;
    unsigned short* xproj = (unsigned short*)(pk_out + PK_OUT_ELEMS);  // 8.4 MB planar bf16
    float* out     = (float*)d_out;

    hipLaunchKernelGGL(k_pack, dim3(240), dim3(256), 0, stream,
                       w_in, w_off, w_msk, w_out, pk_in, pk_comb, pk_out);
    hipLaunchKernelGGL(k_fm, dim3(NPIX / PXB), dim3(256), 0, stream,
                       x, dw_w, dw_b, ln_g, ln_b, pk_in, b_in,
                       pk_comb, b_off, b_msk, xproj, out);
    hipLaunchKernelGGL(k_samp, dim3(NPIX / PXB), dim3(256), 0, stream,
                       xproj, pk_out, b_out, out);
}

// Round 13
// 59.970 us; speedup vs baseline: 1.7596x; 1.7596x over previous
//
#include <hip/hip_runtime.h>
#include <math.h>

#define NB 8
#define H 64
#define W 64
#define C 128
#define G 8
#define GC 16
#define P 9
#define NPIX (NB * H * W)     // 32768
#define N_OFF 144
#define N_MSK 72
#define PXB 32
#define RECW 232              // record row stride in u16 (464 B)
#define PK_IN_ELEMS   (8 * 4 * 64 * 8)    // 16384
#define PK_COMB_ELEMS (14 * 4 * 64 * 8)   // 28672
#define PK_OUT_ELEMS  (8 * 4 * 64 * 8)    // 16384

using bf16x8 = __attribute__((ext_vector_type(8))) short;
using f32x4  = __attribute__((ext_vector_type(4))) float;
using u32x4  = __attribute__((ext_vector_type(4))) unsigned;

__device__ __forceinline__ short f2bf(float f) {
    union { float fv; unsigned u; } v; v.fv = f;
    unsigned r = v.u + 0x7fffu + ((v.u >> 16) & 1u);
    return (short)(r >> 16);
}

// ---------------- K0: pack weights into MFMA B-fragment order, bf16 --------
__global__ __launch_bounds__(256) void k_pack(
    const float* __restrict__ w_in, const float* __restrict__ w_off,
    const float* __restrict__ w_msk, const float* __restrict__ w_out,
    short* __restrict__ pk_in, short* __restrict__ pk_comb, short* __restrict__ pk_out)
{
    const int tid = blockIdx.x * 256 + threadIdx.x;
    int p, which;
    if (tid < PK_IN_ELEMS) { p = tid; which = 0; }
    else if (tid < PK_IN_ELEMS + PK_COMB_ELEMS) { p = tid - PK_IN_ELEMS; which = 1; }
    else if (tid < PK_IN_ELEMS + PK_COMB_ELEMS + PK_OUT_ELEMS) { p = tid - PK_IN_ELEMS - PK_COMB_ELEMS; which = 2; }
    else return;
    const int e = p & 7, lane = (p >> 3) & 63, kt = (p >> 9) & 3, nt = p >> 11;
    const int k = kt * 32 + (lane >> 4) * 8 + e;
    const int n = nt * 16 + (lane & 15);
    float v;
    if (which == 0) {
        v = w_in[k * C + n];
        pk_in[p] = f2bf(v);
    } else if (which == 1) {
        if (n < N_OFF) v = w_off[k * N_OFF + n];
        else if (n < N_OFF + N_MSK) v = w_msk[k * N_MSK + (n - N_OFF)];
        else v = 0.f;
        pk_comb[p] = f2bf(v);
    } else {
        v = w_out[k * C + n];
        pk_out[p] = f2bf(v);
    }
}

// ---- K_fm: dwconv+LN+GELU + inproj MFMA -> xproj planar ----
// ----       + offset/mask MFMA + softmax -> 448B/px records in out slots ---
__global__ __launch_bounds__(256, 2) void k_fm(
    const float* __restrict__ x, const float* __restrict__ dw_w,
    const float* __restrict__ dw_b, const float* __restrict__ ln_g,
    const float* __restrict__ ln_b, const short* __restrict__ pk_in,
    const float* __restrict__ b_in, const short* __restrict__ pk_comb,
    const float* __restrict__ b_off, const float* __restrict__ b_msk,
    unsigned short* __restrict__ xproj, float* __restrict__ out)
{
    __shared__ __align__(16) short xa[PXB * C];
    __shared__ __align__(16) short x1s[PXB * C];
    __shared__ unsigned short recs[PXB * RECW];
    __shared__ float part[PXB][8][2];
    __shared__ float stats[PXB][2];

    const int t = threadIdx.x;
    const int n = blockIdx.x & 7;
    const int local = blockIdx.x >> 3;
    const int y = local >> 1;
    const int xb = (local & 1) * PXB;
    const int gpix0 = (n * H + y) * W + xb;

    const int px = t >> 3;
    const int c8 = t & 7;
    const int c0 = c8 * 16;
    const int gpx = gpix0 + px;

    float a[16];
    #pragma unroll
    for (int q = 0; q < 4; ++q) {
        f32x4 v = *(const f32x4*)(dw_b + c0 + q * 4);
        #pragma unroll
        for (int e = 0; e < 4; ++e) a[q * 4 + e] = v[e];
    }
    #pragma unroll
    for (int ky = 0; ky < 3; ++ky) {
        const int yy = y + ky - 1;
        if (yy < 0 || yy >= H) continue;
        #pragma unroll
        for (int kx = 0; kx < 3; ++kx) {
            const int xx = xb + px + kx - 1;
            if (xx < 0 || xx >= W) continue;
            const float* xp = x + ((size_t)(n * H + yy) * W + xx) * C + c0;
            const float* wp = dw_w + (ky * 3 + kx) * C + c0;
            #pragma unroll
            for (int q = 0; q < 4; ++q) {
                f32x4 xv = *(const f32x4*)(xp + q * 4);
                f32x4 wv = *(const f32x4*)(wp + q * 4);
                #pragma unroll
                for (int e = 0; e < 4; ++e)
                    a[q * 4 + e] = fmaf(xv[e], wv[e], a[q * 4 + e]);
            }
        }
    }
    {
        const float* cp = x + (size_t)gpx * C + c0;
        const int sw = (px & 7) << 4;
        #pragma unroll
        for (int h = 0; h < 2; ++h) {
            f32x4 v0 = *(const f32x4*)(cp + h * 8);
            f32x4 v1 = *(const f32x4*)(cp + h * 8 + 4);
            bf16x8 pk;
            #pragma unroll
            for (int e = 0; e < 4; ++e) { pk[e] = f2bf(v0[e]); pk[4 + e] = f2bf(v1[e]); }
            *(bf16x8*)((char*)xa + px * 256 + ((c8 * 32 + h * 16) ^ sw)) = pk;
        }
    }
    {
        float s = 0.f, sq = 0.f;
        #pragma unroll
        for (int cc = 0; cc < 16; ++cc) { s += a[cc]; sq = fmaf(a[cc], a[cc], sq); }
        part[px][c8][0] = s;
        part[px][c8][1] = sq;
    }
    __syncthreads();
    if (t < PXB) {
        float S = 0.f, Q = 0.f;
        #pragma unroll
        for (int q = 0; q < 8; ++q) { S += part[t][q][0]; Q += part[t][q][1]; }
        const float mu = S * (1.f / C);
        const float va = Q * (1.f / C) - mu * mu;
        stats[t][0] = mu;
        stats[t][1] = rsqrtf(va + 1e-6f);
    }
    __syncthreads();
    {
        const float mu = stats[px][0], rs = stats[px][1];
        const int sw = (px & 7) << 4;
        #pragma unroll
        for (int h = 0; h < 2; ++h) {
            bf16x8 pk;
            #pragma unroll
            for (int e = 0; e < 8; ++e) {
                const int cc = h * 8 + e;
                float v = (a[cc] - mu) * rs * ln_g[c0 + cc] + ln_b[c0 + cc];
                pk[e] = f2bf(v * 0.5f * (1.f + erff(v * 0.70710678118654752f)));
            }
            *(bf16x8*)((char*)x1s + px * 256 + ((c8 * 32 + h * 16) ^ sw)) = pk;
        }
    }
    __syncthreads();

    {
        const int w = t >> 6, l = t & 63;
        const int swA = (l & 7) << 4;
        bf16x8 aA[2][4], aB[2][4];
        #pragma unroll
        for (int mt = 0; mt < 2; ++mt) {
            const int m = mt * 16 + (l & 15);
            #pragma unroll
            for (int kt = 0; kt < 4; ++kt) {
                const int byte = m * 256 + ((kt * 64 + (l >> 4) * 16) ^ swA);
                aA[mt][kt] = *(const bf16x8*)((char*)xa + byte);
                aB[mt][kt] = *(const bf16x8*)((char*)x1s + byte);
            }
        }
        #pragma unroll
        for (int i = 0; i < 2; ++i) {
            const int nt = w + i * 4;
            bf16x8 bf[4];
            const short* bp = pk_in + nt * 2048 + l * 8;
            #pragma unroll
            for (int kt = 0; kt < 4; ++kt) bf[kt] = *(const bf16x8*)(bp + kt * 512);
            const float bias = b_in[nt * 16 + (l & 15)];
            #pragma unroll
            for (int mt = 0; mt < 2; ++mt) {
                f32x4 acc = {0.f, 0.f, 0.f, 0.f};
                #pragma unroll
                for (int kt = 0; kt < 4; ++kt)
                    acc = __builtin_amdgcn_mfma_f32_16x16x32_bf16(aA[mt][kt], bf[kt], acc, 0, 0, 0);
                const int prow = gpix0 + mt * 16 + (l >> 4) * 4;
                #pragma unroll
                for (int r = 0; r < 4; ++r)
                    xproj[(size_t)(nt * NPIX + prow + r) * 16 + (l & 15)] =
                        (unsigned short)f2bf(acc[r] + bias);
            }
        }
        #pragma unroll
        for (int i = 0; i < 4; ++i) {
            const int nt = w + i * 4;
            if (nt < 14) {
                bf16x8 bf[4];
                const short* bp = pk_comb + nt * 2048 + l * 8;
                #pragma unroll
                for (int kt = 0; kt < 4; ++kt) bf[kt] = *(const bf16x8*)(bp + kt * 512);
                const int col = nt * 16 + (l & 15);
                int dcol = col;
                float bias = 0.f;
                bool valid = true;
                if (col < N_OFF) bias = b_off[col];
                else {
                    const int cm = col - N_OFF;
                    if (cm < N_MSK) {
                        const int g = (cm * 57) >> 9;
                        dcol = 144 + g * 10 + (cm - 9 * g);
                        bias = b_msk[cm];
                    } else valid = false;
                }
                #pragma unroll
                for (int mt = 0; mt < 2; ++mt) {
                    f32x4 acc = {0.f, 0.f, 0.f, 0.f};
                    #pragma unroll
                    for (int kt = 0; kt < 4; ++kt)
                        acc = __builtin_amdgcn_mfma_f32_16x16x32_bf16(aB[mt][kt], bf[kt], acc, 0, 0, 0);
                    if (valid) {
                        const int pr0 = mt * 16 + (l >> 4) * 4;
                        #pragma unroll
                        for (int r = 0; r < 4; ++r)
                            recs[(pr0 + r) * RECW + dcol] = (unsigned short)f2bf(acc[r] + bias);
                    }
                }
            }
        }
    }
    __syncthreads();

    {
        const int spx = t >> 3, g = t & 7;
        unsigned short* row = recs + spx * RECW + 144 + g * 10;
        float lg[P];
        #pragma unroll
        for (int p = 0; p < P; ++p) lg[p] = __uint_as_float(((unsigned)row[p]) << 16);
        float mx = lg[0];
        #pragma unroll
        for (int p2 = 1; p2 < P; ++p2) mx = fmaxf(mx, lg[p2]);
        float e[P], s = 0.f;
        #pragma unroll
        for (int p2 = 0; p2 < P; ++p2) { e[p2] = expf(lg[p2] - mx); s += e[p2]; }
        const float inv = 1.0f / s;
        #pragma unroll
        for (int p2 = 0; p2 < P; ++p2) row[p2] = (unsigned short)f2bf(e[p2] * inv);
    }
    __syncthreads();

    {
        const int spx = t >> 3, q0 = t & 7;
        const char* srcL = (const char*)recs + spx * (RECW * 2);
        char* dst = (char*)out + (size_t)(gpix0 + spx) * 512;
        #pragma unroll
        for (int h = 0; h < 4; ++h) {
            const int q = q0 + h * 8;
            if (q < 28)
                *(bf16x8*)(dst + q * 16) = *(const bf16x8*)(srcL + q * 16);
        }
    }
}

// ---- K_samp: register 5x5 stencil + direct L2 gather + out-proj MFMA ----
__global__ __launch_bounds__(256, 2) void k_samp(
    const unsigned short* __restrict__ xproj, const short* __restrict__ pk_out,
    const float* __restrict__ b_out, float* __restrict__ out)
{
    __shared__ __align__(16) short smp[PXB * C];   // 8 KB only

    const int t = threadIdx.x;
    const int n = blockIdx.x & 7;
    const int local = blockIdx.x >> 3;
    const int y = local >> 1;
    const int xb = (local & 1) * PXB;
    const int gpix0 = (n * H + y) * W + xb;
    const int imgbase = n * (H * W);

    const int spx = t & 31;
    const int g = t >> 5;             // 0..7
    const int xabs = xb + spx;
    const int swz = (spx & 7) << 4;
    const unsigned* slot = (const unsigned*)((const char*)out +
                           (size_t)(gpix0 + spx) * 512);

    // ---- build 5x5 stencil in registers (static indices only) ----
    float cf[25];
    #pragma unroll
    for (int i = 0; i < 25; ++i) cf[i] = 0.f;
    float amax = 0.f;
    {
        u32x4 a0 = *(const u32x4*)(slot + g * 9);
        u32x4 a1 = *(const u32x4*)(slot + g * 9 + 4);
        const unsigned ov8 = slot[g * 9 + 8];
        u32x4 b0 = *(const u32x4*)(slot + 72 + 5 * g);
        const unsigned pb4 = slot[72 + 5 * g + 4];
        #pragma unroll
        for (int p = 0; p < P; ++p) {
            const unsigned ovp = (p < 4) ? a0[p & 3] : (p < 8) ? a1[p & 3] : ov8;
            const unsigned pu = (p < 8) ? b0[p >> 1] : pb4;
            const float m = (p & 1) ? __uint_as_float(pu & 0xffff0000u)
                                    : __uint_as_float(pu << 16);
            const float ox = __uint_as_float(ovp << 16);
            const float oy = __uint_as_float(ovp & 0xffff0000u);
            amax = fmaxf(amax, fmaxf(fabsf(ox), fabsf(oy)));
            const float fx = floorf(ox);          // -1 or 0 when |ox|<1
            const float fy = floorf(oy);
            const float wx = ox - fx, wy = oy - fy;
            const bool lox = fx < -0.5f;
            const bool loy = fy < -0.5f;
            const float wc0 = lox ? (1.f - wx) : 0.f;
            const float wc1 = lox ? wx : (1.f - wx);
            const float wc2 = lox ? 0.f : wx;
            const float wr0 = loy ? (1.f - wy) : 0.f;
            const float wr1 = loy ? wy : (1.f - wy);
            const float wr2 = loy ? 0.f : wy;
            const float mr0 = m * wr0, mr1 = m * wr1, mr2 = m * wr2;
            const int dxp = p / 3 - 1, dyp = p % 3 - 1;
            const int base = (dyp + 1) * 5 + (dxp + 1);
            cf[base + 0]      = fmaf(wc0, mr0, cf[base + 0]);
            cf[base + 1]      = fmaf(wc1, mr0, cf[base + 1]);
            cf[base + 2]      = fmaf(wc2, mr0, cf[base + 2]);
            cf[base + 5]      = fmaf(wc0, mr1, cf[base + 5]);
            cf[base + 6]      = fmaf(wc1, mr1, cf[base + 6]);
            cf[base + 7]      = fmaf(wc2, mr1, cf[base + 7]);
            cf[base + 10]     = fmaf(wc0, mr2, cf[base + 10]);
            cf[base + 11]     = fmaf(wc1, mr2, cf[base + 11]);
            cf[base + 12]     = fmaf(wc2, mr2, cf[base + 12]);
        }
    }
    // edge validity masks (zero weights outside image)
    #pragma unroll
    for (int j = 0; j < 5; ++j) {
        const int xc = xabs + j - 2;
        if (!((xc >= 0) & (xc < W))) {
            #pragma unroll
            for (int i = 0; i < 5; ++i) cf[i * 5 + j] = 0.f;
        }
    }
    #pragma unroll
    for (int i = 0; i < 5; ++i) {
        const int yc = y + i - 2;
        if (!((yc >= 0) & (yc < H))) {
            #pragma unroll
            for (int j = 0; j < 5; ++j) cf[i * 5 + j] = 0.f;
        }
    }

    // clamped addresses (invalid cells have cf=0, clamp keeps loads in-bounds)
    const char* pb = (const char*)(xproj + (size_t)(g * NPIX + imgbase) * 16);
    int rowoff[5], coloff[5];
    #pragma unroll
    for (int i = 0; i < 5; ++i) {
        rowoff[i] = min(max(y + i - 2, 0), H - 1) * (W * 32);
        coloff[i] = min(max(xabs + i - 2, 0), W - 1) * 32;
    }

    float acc[16];
    #pragma unroll
    for (int q = 0; q < 16; ++q) acc[q] = 0.f;

    if (amax < 1.0f) {
        #pragma unroll
        for (int i = 0; i < 5; ++i) {
            #pragma unroll
            for (int j = 0; j < 5; ++j) {
                const float c = cf[i * 5 + j];
                const char* ap = pb + (rowoff[i] + coloff[j]);
                u32x4 v0 = *(const u32x4*)ap;
                u32x4 v1 = *(const u32x4*)(ap + 16);
                #pragma unroll
                for (int e = 0; e < 4; ++e) {
                    acc[2 * e]     = fmaf(c, __uint_as_float(v0[e] << 16), acc[2 * e]);
                    acc[2 * e + 1] = fmaf(c, __uint_as_float(v0[e] & 0xffff0000u), acc[2 * e + 1]);
                    acc[8 + 2 * e]     = fmaf(c, __uint_as_float(v1[e] << 16), acc[8 + 2 * e]);
                    acc[8 + 2 * e + 1] = fmaf(c, __uint_as_float(v1[e] & 0xffff0000u), acc[8 + 2 * e + 1]);
                }
            }
        }
    } else {
        // exact fallback for |offset| >= 1 (rare): per-tap bilinear from global
        for (int p = 0; p < P; ++p) {
            const unsigned ovp = slot[g * 9 + p];
            const unsigned pu = slot[72 + 5 * g + (p >> 1)];
            const float m = (p & 1) ? __uint_as_float(pu & 0xffff0000u)
                                    : __uint_as_float(pu << 16);
            const float ux = (float)(xabs + (p / 3) - 1) + __uint_as_float(ovp << 16);
            const float uy = (float)(y + (p % 3) - 1) + __uint_as_float(ovp & 0xffff0000u);
            const float fx = floorf(ux), fy = floorf(uy);
            const float wx = ux - fx, wy = uy - fy;
            const int x0 = (int)fx, y0 = (int)fy;
            float w4[4];
            w4[0] = m * (1.f - wx) * (1.f - wy);
            w4[1] = m * wx * (1.f - wy);
            w4[2] = m * (1.f - wx) * wy;
            w4[3] = m * wx * wy;
            if (!((x0 >= 0) & (x0 < W)))       { w4[0] = 0.f; w4[2] = 0.f; }
            if (!((x0 >= -1) & (x0 < W - 1)))  { w4[1] = 0.f; w4[3] = 0.f; }
            if (!((y0 >= 0) & (y0 < H)))       { w4[0] = 0.f; w4[1] = 0.f; }
            if (!((y0 >= -1) & (y0 < H - 1)))  { w4[2] = 0.f; w4[3] = 0.f; }
            const int xc[2] = { min(max(x0, 0), W - 1), min(max(x0 + 1, 0), W - 1) };
            const int yc[2] = { min(max(y0, 0), H - 1), min(max(y0 + 1, 0), H - 1) };
            for (int cn = 0; cn < 4; ++cn) {
                const float wgt = w4[cn];
                if (wgt == 0.f) continue;
                const char* ap = pb + ((size_t)(yc[cn >> 1] * W + xc[cn & 1]) * 32);
                u32x4 v0 = *(const u32x4*)ap;
                u32x4 v1 = *(const u32x4*)(ap + 16);
                #pragma unroll
                for (int e = 0; e < 4; ++e) {
                    acc[2 * e]     = fmaf(wgt, __uint_as_float(v0[e] << 16), acc[2 * e]);
                    acc[2 * e + 1] = fmaf(wgt, __uint_as_float(v0[e] & 0xffff0000u), acc[2 * e + 1]);
                    acc[8 + 2 * e]     = fmaf(wgt, __uint_as_float(v1[e] << 16), acc[8 + 2 * e]);
                    acc[8 + 2 * e + 1] = fmaf(wgt, __uint_as_float(v1[e] & 0xffff0000u), acc[8 + 2 * e + 1]);
                }
            }
        }
    }

    // write 16 ch -> smp (bf16, swizzled)
    #pragma unroll
    for (int h = 0; h < 2; ++h) {
        bf16x8 pk;
        #pragma unroll
        for (int e = 0; e < 8; ++e) pk[e] = f2bf(acc[h * 8 + e]);
        *(bf16x8*)((char*)smp + spx * 256 + ((g * 32 + h * 16) ^ swz)) = pk;
    }
    __syncthreads();

    // ---- output projection via MFMA (nt-partitioned) ----
    {
        const int w = t >> 6, l = t & 63;
        const int swA = (l & 7) << 4;
        bf16x8 aS[2][4];
        #pragma unroll
        for (int mt = 0; mt < 2; ++mt) {
            const int m = mt * 16 + (l & 15);
            #pragma unroll
            for (int kt = 0; kt < 4; ++kt)
                aS[mt][kt] = *(const bf16x8*)((char*)smp + m * 256 +
                                              ((kt * 64 + (l >> 4) * 16) ^ swA));
        }
        #pragma unroll
        for (int i = 0; i < 2; ++i) {
            const int nt = w + i * 4;
            bf16x8 bf[4];
            const short* bp = pk_out + nt * 2048 + l * 8;
            #pragma unroll
            for (int kt = 0; kt < 4; ++kt) bf[kt] = *(const bf16x8*)(bp + kt * 512);
            const float bias = b_out[nt * 16 + (l & 15)];
            #pragma unroll
            for (int mt = 0; mt < 2; ++mt) {
                f32x4 acc2 = {0.f, 0.f, 0.f, 0.f};
                #pragma unroll
                for (int kt = 0; kt < 4; ++kt)
                    acc2 = __builtin_amdgcn_mfma_f32_16x16x32_bf16(aS[mt][kt], bf[kt], acc2, 0, 0, 0);
                const int row0 = gpix0 + mt * 16 + (l >> 4) * 4;
                #pragma unroll
                for (int r = 0; r < 4; ++r)
                    out[(size_t)(row0 + r) * C + nt * 16 + (l & 15)] = acc2[r] + bias;
            }
        }
    }
}

extern "C" void kernel_launch(void* const* d_in, const int* in_sizes, int n_in,
                              void* d_out, int out_size, void* d_ws, size_t ws_size,
                              hipStream_t stream)
{
    const float* x     = (const float*)d_in[0];
    const float* w_in  = (const float*)d_in[1];
    const float* b_in  = (const float*)d_in[2];
    const float* dw_w  = (const float*)d_in[3];
    const float* dw_b  = (const float*)d_in[4];
    const float* ln_g  = (const float*)d_in[5];
    const float* ln_b  = (const float*)d_in[6];
    const float* w_off = (const float*)d_in[7];
    const float* b_off = (const float*)d_in[8];
    const float* w_msk = (const float*)d_in[9];
    const float* b_msk = (const float*)d_in[10];
    const float* w_out = (const float*)d_in[11];
    const float* b_out = (const float*)d_in[12];

    short* pk_in   = (short*)d_ws;
    short* pk_comb = pk_in + PK_IN_ELEMS;
    short* pk_out  = pk_comb + PK_COMB_ELEMS;
    unsigned short* xproj = (unsigned short*)(pk_out + PK_OUT_ELEMS);  // 8.4 MB planar bf16
    float* out     = (float*)d_out;

    hipLaunchKernelGGL(k_pack, dim3(240), dim3(256), 0, stream,
                       w_in, w_off, w_msk, w_out, pk_in, pk_comb, pk_out);
    hipLaunchKernelGGL(k_fm, dim3(NPIX / PXB), dim3(256), 0, stream,
                       x, dw_w, dw_b, ln_g, ln_b, pk_in, b_in,
                       pk_comb, b_off, b_msk, xproj, out);
    hipLaunchKernelGGL(k_samp, dim3(NPIX / PXB), dim3(256), 0, stream,
                       xproj, pk_out, b_out, out);
}

// Round 14
// 50.463 us; speedup vs baseline: 2.0911x; 1.1884x over previous
//
#include <hip/hip_runtime.h>
#include <math.h>

#define NB 8
#define H 64
#define W 64
#define C 128
#define G 8
#define GC 16
#define P 9
#define NPIX (NB * H * W)     // 32768
#define N_OFF 144
#define N_MSK 72
#define PXB 32
#define RECW 232              // record row stride in u16 (464 B)
#define PK_IN_ELEMS   (8 * 4 * 64 * 8)    // 16384
#define PK_COMB_ELEMS (14 * 4 * 64 * 8)   // 28672
#define PK_OUT_ELEMS  (8 * 4 * 64 * 8)    // 16384

using bf16x8 = __attribute__((ext_vector_type(8))) short;
using f32x4  = __attribute__((ext_vector_type(4))) float;
using u32x4  = __attribute__((ext_vector_type(4))) unsigned;

__device__ __forceinline__ short f2bf(float f) {
    union { float fv; unsigned u; } v; v.fv = f;
    unsigned r = v.u + 0x7fffu + ((v.u >> 16) & 1u);
    return (short)(r >> 16);
}

// ---------------- K0: pack weights into MFMA B-fragment order, bf16 --------
__global__ __launch_bounds__(256) void k_pack(
    const float* __restrict__ w_in, const float* __restrict__ w_off,
    const float* __restrict__ w_msk, const float* __restrict__ w_out,
    short* __restrict__ pk_in, short* __restrict__ pk_comb, short* __restrict__ pk_out)
{
    const int tid = blockIdx.x * 256 + threadIdx.x;
    int p, which;
    if (tid < PK_IN_ELEMS) { p = tid; which = 0; }
    else if (tid < PK_IN_ELEMS + PK_COMB_ELEMS) { p = tid - PK_IN_ELEMS; which = 1; }
    else if (tid < PK_IN_ELEMS + PK_COMB_ELEMS + PK_OUT_ELEMS) { p = tid - PK_IN_ELEMS - PK_COMB_ELEMS; which = 2; }
    else return;
    const int e = p & 7, lane = (p >> 3) & 63, kt = (p >> 9) & 3, nt = p >> 11;
    const int k = kt * 32 + (lane >> 4) * 8 + e;
    const int n = nt * 16 + (lane & 15);
    float v;
    if (which == 0) {
        v = w_in[k * C + n];
        pk_in[p] = f2bf(v);
    } else if (which == 1) {
        if (n < N_OFF) v = w_off[k * N_OFF + n];
        else if (n < N_OFF + N_MSK) v = w_msk[k * N_MSK + (n - N_OFF)];
        else v = 0.f;
        pk_comb[p] = f2bf(v);
    } else {
        v = w_out[k * C + n];
        pk_out[p] = f2bf(v);
    }
}

// ---- K_fm: dwconv+LN+GELU + inproj MFMA -> xproj planar ----
// ----       + offset/mask MFMA + softmax -> 448B/px records in out slots ---
__global__ __launch_bounds__(256, 2) void k_fm(
    const float* __restrict__ x, const float* __restrict__ dw_w,
    const float* __restrict__ dw_b, const float* __restrict__ ln_g,
    const float* __restrict__ ln_b, const short* __restrict__ pk_in,
    const float* __restrict__ b_in, const short* __restrict__ pk_comb,
    const float* __restrict__ b_off, const float* __restrict__ b_msk,
    unsigned short* __restrict__ xproj, float* __restrict__ out)
{
    __shared__ __align__(16) short xa[PXB * C];       // 8 KB center-x bf16 swizzled
    __shared__ __align__(16) short x1s[PXB * C];      // 8 KB GELU(LN(dwconv))
    __shared__ unsigned short recs[PXB * RECW];       // 14.5 KB records

    const int t = threadIdx.x;
    const int n = blockIdx.x & 7;
    const int local = blockIdx.x >> 3;
    const int y = local >> 1;
    const int xb = (local & 1) * PXB;
    const int gpix0 = (n * H + y) * W + xb;

    const int px = t >> 3;
    const int c8 = t & 7;
    const int cb = c8 * 4;          // thread channels: cb + q*32 + e
    const int gpx = gpix0 + px;
    const int sw = (px & 7) << 4;

    // ---- phase A: depthwise 3x3 (zeros pad), lane-contiguous channel map ----
    float a[16];
    #pragma unroll
    for (int q = 0; q < 4; ++q) {
        f32x4 v = *(const f32x4*)(dw_b + cb + q * 32);
        #pragma unroll
        for (int e = 0; e < 4; ++e) a[q * 4 + e] = v[e];
    }
    #pragma unroll
    for (int ky = 0; ky < 3; ++ky) {
        const int yy = y + ky - 1;
        if (yy < 0 || yy >= H) continue;
        #pragma unroll
        for (int kx = 0; kx < 3; ++kx) {
            const int xx = xb + px + kx - 1;
            if (xx < 0 || xx >= W) continue;
            const float* xp = x + ((size_t)(n * H + yy) * W + xx) * C;
            const float* wp = dw_w + (ky * 3 + kx) * C;
            #pragma unroll
            for (int q = 0; q < 4; ++q) {
                f32x4 xv = *(const f32x4*)(xp + cb + q * 32);
                f32x4 wv = *(const f32x4*)(wp + cb + q * 32);
                #pragma unroll
                for (int e = 0; e < 4; ++e)
                    a[q * 4 + e] = fmaf(xv[e], wv[e], a[q * 4 + e]);
            }
        }
    }
    // stash center pixel bf16 -> xa (8B writes, same swizzled layout)
    {
        const float* cp = x + (size_t)gpx * C;
        #pragma unroll
        for (int q = 0; q < 4; ++q) {
            f32x4 v = *(const f32x4*)(cp + cb + q * 32);
            const unsigned lo = ((unsigned)(unsigned short)f2bf(v[0])) |
                                (((unsigned)(unsigned short)f2bf(v[1])) << 16);
            const unsigned hi = ((unsigned)(unsigned short)f2bf(v[2])) |
                                (((unsigned)(unsigned short)f2bf(v[3])) << 16);
            *(unsigned long long*)((char*)xa + px * 256 + ((cb * 2 + q * 64) ^ sw)) =
                ((unsigned long long)hi << 32) | lo;
        }
    }
    // LN stats via 8-lane shuffle reduce (threads of one px are 8 consecutive lanes)
    float mu, rsg;
    {
        float s = 0.f, sq = 0.f;
        #pragma unroll
        for (int cc = 0; cc < 16; ++cc) { s += a[cc]; sq = fmaf(a[cc], a[cc], sq); }
        #pragma unroll
        for (int d = 1; d < 8; d <<= 1) {
            s += __shfl_xor(s, d);
            sq += __shfl_xor(sq, d);
        }
        mu = s * (1.f / C);
        const float va = sq * (1.f / C) - mu * mu;
        rsg = rsqrtf(va + 1e-6f);
    }
    // LN affine + GELU -> x1s (8B writes)
    #pragma unroll
    for (int q = 0; q < 4; ++q) {
        f32x4 gv = *(const f32x4*)(ln_g + cb + q * 32);
        f32x4 bv = *(const f32x4*)(ln_b + cb + q * 32);
        unsigned short h4[4];
        #pragma unroll
        for (int e = 0; e < 4; ++e) {
            float v = (a[q * 4 + e] - mu) * rsg * gv[e] + bv[e];
            h4[e] = (unsigned short)f2bf(v * 0.5f * (1.f + erff(v * 0.70710678118654752f)));
        }
        const unsigned lo = ((unsigned)h4[0]) | (((unsigned)h4[1]) << 16);
        const unsigned hi = ((unsigned)h4[2]) | (((unsigned)h4[3]) << 16);
        *(unsigned long long*)((char*)x1s + px * 256 + ((cb * 2 + q * 64) ^ sw)) =
            ((unsigned long long)hi << 32) | lo;
    }
    __syncthreads();

    // ---- phase B: inproj MFMA (xa) + comb MFMA (x1s), nt-partitioned ----
    {
        const int w = t >> 6, l = t & 63;
        const int swA = (l & 7) << 4;
        bf16x8 aA[2][4], aB[2][4];
        #pragma unroll
        for (int mt = 0; mt < 2; ++mt) {
            const int m = mt * 16 + (l & 15);
            #pragma unroll
            for (int kt = 0; kt < 4; ++kt) {
                const int byte = m * 256 + ((kt * 64 + (l >> 4) * 16) ^ swA);
                aA[mt][kt] = *(const bf16x8*)((char*)xa + byte);
                aB[mt][kt] = *(const bf16x8*)((char*)x1s + byte);
            }
        }
        #pragma unroll
        for (int i = 0; i < 2; ++i) {
            const int nt = w + i * 4;
            bf16x8 bf[4];
            const short* bp = pk_in + nt * 2048 + l * 8;
            #pragma unroll
            for (int kt = 0; kt < 4; ++kt) bf[kt] = *(const bf16x8*)(bp + kt * 512);
            const float bias = b_in[nt * 16 + (l & 15)];
            #pragma unroll
            for (int mt = 0; mt < 2; ++mt) {
                f32x4 acc = {0.f, 0.f, 0.f, 0.f};
                #pragma unroll
                for (int kt = 0; kt < 4; ++kt)
                    acc = __builtin_amdgcn_mfma_f32_16x16x32_bf16(aA[mt][kt], bf[kt], acc, 0, 0, 0);
                const int prow = gpix0 + mt * 16 + (l >> 4) * 4;
                #pragma unroll
                for (int r = 0; r < 4; ++r)
                    xproj[(size_t)(nt * NPIX + prow + r) * 16 + (l & 15)] =
                        (unsigned short)f2bf(acc[r] + bias);
            }
        }
        #pragma unroll
        for (int i = 0; i < 4; ++i) {
            const int nt = w + i * 4;
            if (nt < 14) {
                bf16x8 bf[4];
                const short* bp = pk_comb + nt * 2048 + l * 8;
                #pragma unroll
                for (int kt = 0; kt < 4; ++kt) bf[kt] = *(const bf16x8*)(bp + kt * 512);
                const int col = nt * 16 + (l & 15);
                int dcol = col;
                float bias = 0.f;
                bool valid = true;
                if (col < N_OFF) bias = b_off[col];
                else {
                    const int cm = col - N_OFF;
                    if (cm < N_MSK) {
                        const int g = (cm * 57) >> 9;
                        dcol = 144 + g * 10 + (cm - 9 * g);
                        bias = b_msk[cm];
                    } else valid = false;
                }
                #pragma unroll
                for (int mt = 0; mt < 2; ++mt) {
                    f32x4 acc = {0.f, 0.f, 0.f, 0.f};
                    #pragma unroll
                    for (int kt = 0; kt < 4; ++kt)
                        acc = __builtin_amdgcn_mfma_f32_16x16x32_bf16(aB[mt][kt], bf[kt], acc, 0, 0, 0);
                    if (valid) {
                        const int pr0 = mt * 16 + (l >> 4) * 4;
                        #pragma unroll
                        for (int r = 0; r < 4; ++r)
                            recs[(pr0 + r) * RECW + dcol] = (unsigned short)f2bf(acc[r] + bias);
                    }
                }
            }
        }
    }
    __syncthreads();

    // ---- phase C: softmax on prob slots ----
    {
        const int spx = t >> 3, g = t & 7;
        unsigned short* row = recs + spx * RECW + 144 + g * 10;
        float lg[P];
        #pragma unroll
        for (int p = 0; p < P; ++p) lg[p] = __uint_as_float(((unsigned)row[p]) << 16);
        float mx = lg[0];
        #pragma unroll
        for (int p2 = 1; p2 < P; ++p2) mx = fmaxf(mx, lg[p2]);
        float e[P], s = 0.f;
        #pragma unroll
        for (int p2 = 0; p2 < P; ++p2) { e[p2] = expf(lg[p2] - mx); s += e[p2]; }
        const float inv = 1.0f / s;
        #pragma unroll
        for (int p2 = 0; p2 < P; ++p2) row[p2] = (unsigned short)f2bf(e[p2] * inv);
    }
    __syncthreads();

    // ---- phase D: coalesced record write to out slots ----
    {
        const int spx = t >> 3, q0 = t & 7;
        const char* srcL = (const char*)recs + spx * (RECW * 2);
        char* dst = (char*)out + (size_t)(gpix0 + spx) * 512;
        #pragma unroll
        for (int h = 0; h < 4; ++h) {
            const int q = q0 + h * 8;
            if (q < 28)
                *(bf16x8*)(dst + q * 16) = *(const bf16x8*)(srcL + q * 16);
        }
    }
}

// ---- K_samp: register 5x5 stencil + LDS window gather + out-proj MFMA ----
#define PADX 41
__global__ __launch_bounds__(256, 2) void k_samp(
    const unsigned short* __restrict__ xproj, const short* __restrict__ pk_out,
    const float* __restrict__ b_out, float* __restrict__ out)
{
    __shared__ __align__(16) short smp[PXB * C];            // 8 KB
    __shared__ __align__(16) u32x4 win[2 * 4 * 5 * PADX];   // 26.2 KB window

    const int t = threadIdx.x;
    const int n = blockIdx.x & 7;
    const int local = blockIdx.x >> 3;
    const int y = local >> 1;
    const int xb = (local & 1) * PXB;
    const int gpix0 = (n * H + y) * W + xb;
    const int imgbase = n * (H * W);

    const int spx = t & 31;
    const int gl = (t >> 5) & 3;
    const int half = t >> 7;
    const int xabs = xb + spx;
    const int swz = (spx & 7) << 4;
    const unsigned* slot = (const unsigned*)((const char*)out +
                           (size_t)(gpix0 + spx) * 512);

    for (int f = 0; f < 2; ++f) {
        const int g = f * 4 + gl;

        // ---- build 5x5 stencil in registers (static indices only) ----
        float cf[25];
        #pragma unroll
        for (int i = 0; i < 25; ++i) cf[i] = 0.f;
        float amax = 0.f;
        {
            u32x4 a0 = *(const u32x4*)(slot + g * 9);
            u32x4 a1 = *(const u32x4*)(slot + g * 9 + 4);
            const unsigned ov8 = slot[g * 9 + 8];
            u32x4 b0 = *(const u32x4*)(slot + 72 + 5 * g);
            const unsigned pb4 = slot[72 + 5 * g + 4];
            #pragma unroll
            for (int p = 0; p < P; ++p) {
                const unsigned ovp = (p < 4) ? a0[p & 3] : (p < 8) ? a1[p & 3] : ov8;
                const unsigned pu = (p < 8) ? b0[p >> 1] : pb4;
                const float m = (p & 1) ? __uint_as_float(pu & 0xffff0000u)
                                        : __uint_as_float(pu << 16);
                const float ox = __uint_as_float(ovp << 16);
                const float oy = __uint_as_float(ovp & 0xffff0000u);
                amax = fmaxf(amax, fmaxf(fabsf(ox), fabsf(oy)));
                const float fx = floorf(ox);
                const float fy = floorf(oy);
                const float wx = ox - fx, wy = oy - fy;
                const bool lox = fx < -0.5f;
                const bool loy = fy < -0.5f;
                const float wc0 = lox ? (1.f - wx) : 0.f;
                const float wc1 = lox ? wx : (1.f - wx);
                const float wc2 = lox ? 0.f : wx;
                const float wr0 = loy ? (1.f - wy) : 0.f;
                const float wr1 = loy ? wy : (1.f - wy);
                const float wr2 = loy ? 0.f : wy;
                const float mr0 = m * wr0, mr1 = m * wr1, mr2 = m * wr2;
                const int dxp = p / 3 - 1, dyp = p % 3 - 1;
                const int base = (dyp + 1) * 5 + (dxp + 1);
                cf[base + 0]  = fmaf(wc0, mr0, cf[base + 0]);
                cf[base + 1]  = fmaf(wc1, mr0, cf[base + 1]);
                cf[base + 2]  = fmaf(wc2, mr0, cf[base + 2]);
                cf[base + 5]  = fmaf(wc0, mr1, cf[base + 5]);
                cf[base + 6]  = fmaf(wc1, mr1, cf[base + 6]);
                cf[base + 7]  = fmaf(wc2, mr1, cf[base + 7]);
                cf[base + 10] = fmaf(wc0, mr2, cf[base + 10]);
                cf[base + 11] = fmaf(wc1, mr2, cf[base + 11]);
                cf[base + 12] = fmaf(wc2, mr2, cf[base + 12]);
            }
        }
        // edge validity masks
        #pragma unroll
        for (int j = 0; j < 5; ++j) {
            const int xc = xabs + j - 2;
            if (!((xc >= 0) & (xc < W))) {
                #pragma unroll
                for (int i = 0; i < 5; ++i) cf[i * 5 + j] = 0.f;
            }
        }
        #pragma unroll
        for (int i = 0; i < 5; ++i) {
            const int yc = y + i - 2;
            if (!((yc >= 0) & (yc < H))) {
                #pragma unroll
                for (int j = 0; j < 5; ++j) cf[i * 5 + j] = 0.f;
            }
        }
        __syncthreads();   // win reusable (prev sampling done)

        // ---- fill window: 4 groups x 5 rows x 40 cols (coalesced global) ----
        for (int e = t; e < 1600; e += 256) {
            const int uh = e & 1;
            const int v = e >> 1;
            const int xs = v % 40;
            const int q2 = v / 40;
            const int rs = q2 % 5;
            const int gs = q2 / 5;
            const int row = min(max(y - 2 + rs, 0), H - 1);
            const int col = min(max(xb - 4 + xs, 0), W - 1);
            win[((uh * 4 + gs) * 5 + rs) * PADX + xs] =
                *(const u32x4*)(xproj +
                    ((size_t)((f * 4 + gs) * NPIX + imgbase + row * W + col)) * 16 + uh * 8);
        }
        __syncthreads();

        // ---- sample 8 channels from LDS window ----
        {
            float acc[8];
            #pragma unroll
            for (int q = 0; q < 8; ++q) acc[q] = 0.f;
            if (amax < 1.0f) {
                const u32x4* wb = win + (half * 4 + gl) * 5 * PADX + spx + 2;
                #pragma unroll
                for (int rr = 0; rr < 5; ++rr) {
                    #pragma unroll
                    for (int cc = 0; cc < 5; ++cc) {
                        const float c = cf[rr * 5 + cc];
                        const u32x4 v = wb[rr * PADX + cc];
                        #pragma unroll
                        for (int e = 0; e < 4; ++e) {
                            acc[2 * e]     = fmaf(c, __uint_as_float(v[e] << 16), acc[2 * e]);
                            acc[2 * e + 1] = fmaf(c, __uint_as_float(v[e] & 0xffff0000u), acc[2 * e + 1]);
                        }
                    }
                }
            } else {
                // rare exact fallback: per-tap bilinear from global plane
                const u32x4* plane4 = (const u32x4*)(xproj + (size_t)(g * NPIX + imgbase) * 16);
                for (int p = 0; p < P; ++p) {
                    const unsigned ovp = slot[g * 9 + p];
                    const unsigned pu = slot[72 + 5 * g + (p >> 1)];
                    const float m = (p & 1) ? __uint_as_float(pu & 0xffff0000u)
                                            : __uint_as_float(pu << 16);
                    const float ux = (float)(xabs + (p / 3) - 1) + __uint_as_float(ovp << 16);
                    const float uy = (float)(y + (p % 3) - 1) + __uint_as_float(ovp & 0xffff0000u);
                    const float fx = floorf(ux), fy = floorf(uy);
                    const float wx = ux - fx, wy = uy - fy;
                    const int x0 = (int)fx, y0 = (int)fy;
                    float w4[4];
                    w4[0] = m * (1.f - wx) * (1.f - wy);
                    w4[1] = m * wx * (1.f - wy);
                    w4[2] = m * (1.f - wx) * wy;
                    w4[3] = m * wx * wy;
                    if (!((x0 >= 0) & (x0 < W)))       { w4[0] = 0.f; w4[2] = 0.f; }
                    if (!((x0 >= -1) & (x0 < W - 1)))  { w4[1] = 0.f; w4[3] = 0.f; }
                    if (!((y0 >= 0) & (y0 < H)))       { w4[0] = 0.f; w4[1] = 0.f; }
                    if (!((y0 >= -1) & (y0 < H - 1)))  { w4[2] = 0.f; w4[3] = 0.f; }
                    const int xc[2] = { min(max(x0, 0), W - 1), min(max(x0 + 1, 0), W - 1) };
                    const int yc[2] = { min(max(y0, 0), H - 1), min(max(y0 + 1, 0), H - 1) };
                    for (int cn = 0; cn < 4; ++cn) {
                        const float wgt = w4[cn];
                        if (wgt == 0.f) continue;
                        const u32x4 v = plane4[(size_t)(yc[cn >> 1] * W + xc[cn & 1]) * 2 + half];
                        #pragma unroll
                        for (int e = 0; e < 4; ++e) {
                            acc[2 * e]     = fmaf(wgt, __uint_as_float(v[e] << 16), acc[2 * e]);
                            acc[2 * e + 1] = fmaf(wgt, __uint_as_float(v[e] & 0xffff0000u), acc[2 * e + 1]);
                        }
                    }
                }
            }
            bf16x8 pk;
            #pragma unroll
            for (int e = 0; e < 8; ++e) pk[e] = f2bf(acc[e]);
            *(bf16x8*)((char*)smp + spx * 256 + ((g * 32 + half * 16) ^ swz)) = pk;
        }
    }
    __syncthreads();

    // ---- output projection via MFMA (nt-partitioned) ----
    {
        const int w = t >> 6, l = t & 63;
        const int swA = (l & 7) << 4;
        bf16x8 aS[2][4];
        #pragma unroll
        for (int mt = 0; mt < 2; ++mt) {
            const int m = mt * 16 + (l & 15);
            #pragma unroll
            for (int kt = 0; kt < 4; ++kt)
                aS[mt][kt] = *(const bf16x8*)((char*)smp + m * 256 +
                                              ((kt * 64 + (l >> 4) * 16) ^ swA));
        }
        #pragma unroll
        for (int i = 0; i < 2; ++i) {
            const int nt = w + i * 4;
            bf16x8 bf[4];
            const short* bp = pk_out + nt * 2048 + l * 8;
            #pragma unroll
            for (int kt = 0; kt < 4; ++kt) bf[kt] = *(const bf16x8*)(bp + kt * 512);
            const float bias = b_out[nt * 16 + (l & 15)];
            #pragma unroll
            for (int mt = 0; mt < 2; ++mt) {
                f32x4 acc2 = {0.f, 0.f, 0.f, 0.f};
                #pragma unroll
                for (int kt = 0; kt < 4; ++kt)
                    acc2 = __builtin_amdgcn_mfma_f32_16x16x32_bf16(aS[mt][kt], bf[kt], acc2, 0, 0, 0);
                const int row0 = gpix0 + mt * 16 + (l >> 4) * 4;
                #pragma unroll
                for (int r = 0; r < 4; ++r)
                    out[(size_t)(row0 + r) * C + nt * 16 + (l & 15)] = acc2[r] + bias;
            }
        }
    }
}

extern "C" void kernel_launch(void* const* d_in, const int* in_sizes, int n_in,
                              void* d_out, int out_size, void* d_ws, size_t ws_size,
                              hipStream_t stream)
{
    const float* x     = (const float*)d_in[0];
    const float* w_in  = (const float*)d_in[1];
    const float* b_in  = (const float*)d_in[2];
    const float* dw_w  = (const float*)d_in[3];
    const float* dw_b  = (const float*)d_in[4];
    const float* ln_g  = (const float*)d_in[5];
    const float* ln_b  = (const float*)d_in[6];
    const float* w_off = (const float*)d_in[7];
    const float* b_off = (const float*)d_in[8];
    const float* w_msk = (const float*)d_in[9];
    const float* b_msk = (const float*)d_in[10];
    const float* w_out = (const float*)d_in[11];
    const float* b_out = (const float*)d_in[12];

    short* pk_in   = (short*)d_ws;
    short* pk_comb = pk_in + PK_IN_ELEMS;
    short* pk_out  = pk_comb + PK_COMB_ELEMS;
    unsigned short* xproj = (unsigned short*)(pk_out + PK_OUT_ELEMS);  // 8.4 MB planar bf16
    float* out     = (float*)d_out;

    hipLaunchKernelGGL(k_pack, dim3(240), dim3(256), 0, stream,
                       w_in, w_off, w_msk, w_out, pk_in, pk_comb, pk_out);
    hipLaunchKernelGGL(k_fm, dim3(NPIX / PXB), dim3(256), 0, stream,
                       x, dw_w, dw_b, ln_g, ln_b, pk_in, b_in,
                       pk_comb, b_off, b_msk, xproj, out);
    hipLaunchKernelGGL(k_samp, dim3(NPIX / PXB), dim3(256), 0, stream,
                       xproj, pk_out, b_out, out);
}